// Round 8
// baseline (332.617 us; speedup 1.0000x reference)
//
#include <hip/hip_runtime.h>
#include <hip/hip_bf16.h>

typedef __bf16 v8bf16 __attribute__((ext_vector_type(8)));
typedef __bf16 v2bf16 __attribute__((ext_vector_type(2)));
typedef float  v4f    __attribute__((ext_vector_type(4)));
typedef float  v16f   __attribute__((ext_vector_type(16)));
typedef unsigned int u32;

#define SEQ     8192
#define DIM     64
#define OUTSEQ  7936
#define WIN     512
#define HALF    256
#define BH      32
#define NCHUNK  15          // full 512-wide chunks per bh
#define MAXT    17          // 1 global tile + 16 window tiles
#define NWG_CH  1920        // 480 chunks * 4 q-tiles (128 q each)

__device__ __forceinline__ v8bf16 cvt8(v4f a, v4f b) {
    v8bf16 r;
    r[0] = (__bf16)a[0]; r[1] = (__bf16)a[1];
    r[2] = (__bf16)a[2]; r[3] = (__bf16)a[3];
    r[4] = (__bf16)b[0]; r[5] = (__bf16)b[1];
    r[6] = (__bf16)b[2]; r[7] = (__bf16)b[3];
    return r;
}

__device__ __forceinline__ v8bf16 load8bf(const float* __restrict__ p) {
    const v4f a = *(const v4f*)p;
    const v4f b = *(const v4f*)(p + 4);
    return cvt8(a, b);
}

// pack two floats to bf16x2 in one dword
__device__ __forceinline__ u32 pk2(float lo, float hi) {
    v2bf16 p; p[0] = (__bf16)lo; p[1] = (__bf16)hi;
    return __builtin_bit_cast(u32, p);
}

// launch_bounds (256,4): (256,8)/(256,6) both spill catastrophically
// (R2: 824MB, R6: 560MB fetch). NO LDS, NO barriers in this version:
// every wave is an independent stream; TLP hides all latency.
__global__ __launch_bounds__(256, 4)
void swa_fwd(const float* __restrict__ qg,
             const float* __restrict__ kg,
             const float* __restrict__ vg,
             float* __restrict__ outg)
{
    // ---- XCD-aware mapping: the 4 q-tiles of one chunk share (id & 7) ----
    const int b = blockIdx.x;
    int bh, qoff, koff, ntiles;
    if (b < NWG_CH) {
        const int x  = b & 7;
        const int j  = b >> 3;        // 0..239
        const int qt = j & 3;
        const int cg = ((j >> 2) << 3) | x;   // chunk id 0..479
        bh = cg / NCHUNK;
        const int c = cg - bh * NCHUNK;
        koff = HALF + c * WIN;
        qoff = koff + qt * 128;
        ntiles = MAXT;
    } else {                          // first half-window block: 2 WGs x 128 q
        const int i = b - NWG_CH;     // 0..63
        bh = i >> 1;
        qoff = (i & 1) * 128;
        koff = 0;
        ntiles = 9;
    }

    const float* qb = qg + (size_t)bh * SEQ * DIM;
    const float* kb = kg + (size_t)bh * SEQ * DIM;
    const float* vb = vg + (size_t)bh * SEQ * DIM;

    const int tid  = threadIdx.x;
    const int wave = tid >> 6;
    const int lane = tid & 63;
    const int l31  = lane & 31;
    const int hi8  = (lane >> 5) * 8;     // k-offset of this half within mfma k=16

    // ---- Q fragments as 32x32x16 *B* operand: B[k=d][n=q], n=l31,
    //      chunk c covers d = c*16 + hi8 + j. Wave covers 32 queries.
    const int qrow = qoff + wave * 32 + l31;
    v8bf16 qf[4];
    {
        const float* qp = qb + (size_t)qrow * DIM + hi8;
        #pragma unroll
        for (int c = 0; c < 4; ++c) qf[c] = load8bf(qp + c * 16);
    }

    // ==== main loop: fully unsynchronized. Per tile:
    //      V A-frags direct from global (coalesced dword runs);
    //      S^T via 32x32 MFMA chain; exp in regs;
    //      pk2 + 4x v_permlane32_swap_b32 build PV B-frags;
    //      O^T = V^T * P^T via 32x32. No LDS, no __syncthreads. ====
    const float cexp = 0.125f * 1.44269504089f;   // scale * log2(e)
    const v16f z16 = {0.f,0.f,0.f,0.f,0.f,0.f,0.f,0.f,
                      0.f,0.f,0.f,0.f,0.f,0.f,0.f,0.f};
    float lsum = 0.f;
    v16f oacc[2];                      // O^T tiles: d 0-31, 32-63; col=q=l31
    oacc[0] = z16; oacc[1] = z16;

    for (int t = 0; t < ntiles; ++t) {
        const int base = (t == 0) ? 0 : koff + (t - 1) * 32;

        // V fragments (A operand of PV) DIRECT from global:
        // A[m=d][k=key], m=l31 -> d = dt*32+l31, k-step ks: key = ks*16+hi8+j.
        // Per (dt,ks,j): lanes 0-31 read V[key][dt*32+0..31] = 128B run.
        v8bf16 vf[2][2];
        #pragma unroll
        for (int dt = 0; dt < 2; ++dt) {
            #pragma unroll
            for (int ks = 0; ks < 2; ++ks) {
                const float* vp = vb + (size_t)(base + ks * 16 + hi8) * DIM + dt * 32 + l31;
                float f[8];
                #pragma unroll
                for (int j = 0; j < 8; ++j) f[j] = vp[j * DIM];
                u32 w[4];
                #pragma unroll
                for (int p = 0; p < 4; ++p) w[p] = pk2(f[2 * p], f[2 * p + 1]);
                vf[dt][ks] = __builtin_bit_cast(v8bf16, w);
            }
        }

        // K fragments as 32x32x16 *A* operand: A[m=key][k=d], m=l31,
        // chunk c: d = c*16 + hi8 + j
        v8bf16 kf[4];
        {
            const float* kp = kb + (size_t)(base + l31) * DIM + hi8;
            #pragma unroll
            for (int c = 0; c < 4; ++c) kf[c] = load8bf(kp + c * 16);
        }

        // S^T[key][q] in one 32x32 acc: col=q=l31, row=key=(r&3)+8*(r>>2)+4*(lane>>5)
        v16f s = __builtin_amdgcn_mfma_f32_32x32x16_bf16(kf[0], qf[0], z16, 0,0,0);
        s = __builtin_amdgcn_mfma_f32_32x32x16_bf16(kf[1], qf[1], s, 0,0,0);
        s = __builtin_amdgcn_mfma_f32_32x32x16_bf16(kf[2], qf[2], s, 0,0,0);
        s = __builtin_amdgcn_mfma_f32_32x32x16_bf16(kf[3], qf[3], s, 0,0,0);

        // exp + pack consecutive keys: P[r/2] = bf16x2(e[r], e[r+1])
        u32 P[8];
        float lacc = 0.f;
        #pragma unroll
        for (int r = 0; r < 16; r += 2) {
            const float ea = __builtin_exp2f(s[r]     * cexp);
            const float eb = __builtin_exp2f(s[r + 1] * cexp);
            lacc += ea + eb;
            P[r >> 1] = pk2(ea, eb);
        }
        lsum += lacc;

        // lo lanes hold key-pairs {0-3,8-11,16-19,24-27}, hi lanes {4-7,...}.
        // v_permlane32_swap_b32 a,b: a.hi <-> b.lo (lane-aligned halves).
        asm volatile("v_permlane32_swap_b32 %0, %1" : "+v"(P[0]), "+v"(P[2]));
        asm volatile("v_permlane32_swap_b32 %0, %1" : "+v"(P[1]), "+v"(P[3]));
        asm volatile("v_permlane32_swap_b32 %0, %1" : "+v"(P[4]), "+v"(P[6]));
        asm volatile("v_permlane32_swap_b32 %0, %1" : "+v"(P[5]), "+v"(P[7]));

        // PV B-frags: B[k=key][n=q], n=l31, k = ks*16 + hi8 + j
        const v8bf16 pf0 = __builtin_bit_cast(v8bf16, *(const u32(*)[4])&P[0]);
        const v8bf16 pf1 = __builtin_bit_cast(v8bf16, *(const u32(*)[4])&P[4]);

        // O^T += V^T * P^T : C[m=d][n=q]
        oacc[0] = __builtin_amdgcn_mfma_f32_32x32x16_bf16(vf[0][0], pf0, oacc[0], 0,0,0);
        oacc[1] = __builtin_amdgcn_mfma_f32_32x32x16_bf16(vf[1][0], pf0, oacc[1], 0,0,0);
        oacc[0] = __builtin_amdgcn_mfma_f32_32x32x16_bf16(vf[0][1], pf1, oacc[0], 0,0,0);
        oacc[1] = __builtin_amdgcn_mfma_f32_32x32x16_bf16(vf[1][1], pf1, oacc[1], 0,0,0);
    }

    // ==== epilogue: lanes (q,lo)/(q,hi) hold disjoint key-halves of lsum ====
    const float l = lsum + __shfl_xor(lsum, 32, 64);
    const float inv = 1.0f / l;
    // oacc row = d = dt*32 + rg*8 + 4*(lane>>5) + i  (regs rg*4+i)
    float* ob = outg + ((size_t)bh * OUTSEQ + qrow) * DIM + (lane >> 5) * 4;
    #pragma unroll
    for (int dt = 0; dt < 2; ++dt) {
        #pragma unroll
        for (int rg = 0; rg < 4; ++rg) {
            v4f rv;
            rv[0] = oacc[dt][rg * 4 + 0] * inv;
            rv[1] = oacc[dt][rg * 4 + 1] * inv;
            rv[2] = oacc[dt][rg * 4 + 2] * inv;
            rv[3] = oacc[dt][rg * 4 + 3] * inv;
            *(v4f*)(ob + dt * 32 + rg * 8) = rv;
        }
    }
}

extern "C" void kernel_launch(void* const* d_in, const int* in_sizes, int n_in,
                              void* d_out, int out_size, void* d_ws, size_t ws_size,
                              hipStream_t stream) {
    const float* q = (const float*)d_in[0];
    const float* k = (const float*)d_in[1];
    const float* v = (const float*)d_in[2];
    float* out = (float*)d_out;

    const int n_wg = NWG_CH + BH * 2;   // 1920 + 64 = 1984
    swa_fwd<<<dim3(n_wg), dim3(256), 0, stream>>>(q, k, v, out);
}